// Round 10
// baseline (168.184 us; speedup 1.0000x reference)
//
#include <hip/hip_runtime.h>
#include <hip/hip_fp16.h>
#include <math.h>

#define N_PTS   65536
#define BATCH   2
#define TOTAL   (BATCH * N_PTS)   // 131072
#define NPACK_DW 16               // dwords per point, neighbor payload (64 B)
#define CPACK   12                // floats per point, center payload
#define EPSB    1e-5f

typedef float  f32x4  __attribute__((ext_vector_type(4)));
typedef _Float16 f16x8 __attribute__((ext_vector_type(8)));

static __device__ inline unsigned h2u(float a, float b) {
    __half2 h = __floats2half2_rn(a, b);
    union { __half2 h; unsigned u; } cv; cv.h = h; return cv.u;
}
static __device__ inline float2 u2f2(unsigned u) {
    union { unsigned u; __half2 h; } cv; cv.u = u; return __half22float2(cv.h);
}
static __device__ inline unsigned pk_max(unsigned a, unsigned b) {
    unsigned r; asm("v_pk_max_f16 %0, %1, %2" : "=v"(r) : "v"(a), "v"(b)); return r;
}
static __device__ inline unsigned pk_fma(unsigned a, unsigned b, unsigned c) {
    unsigned r; asm("v_pk_fma_f16 %0, %1, %2, %3" : "=v"(r) : "v"(a), "v"(b), "v"(c)); return r;
}
static __device__ inline unsigned pkrtz(float a, float b) {
    unsigned r; asm("v_cvt_pkrtz_f16_f32 %0, %1, %2" : "=v"(r) : "v"(a), "v"(b)); return r;
}

// ---------------------------------------------------------------------------
// Kernel 1: per-point precompute. 1 pt/thread, 256-thread blocks.
// Feats read directly from global (9 overlapping dwordx4, L1-resident);
// only the weights live in LDS (6.5 KB) -> occupancy VGPR-bound, not LDS.
//   packN[j] (64 B dwords):
//     0: h(x,y)  1: h(z,Mdot)  2-5: h(Bn0..7)
//     6-13: G int8 (offset-128), byte order [c0,c2,c1,c3] per dword
//     14: scale = max|G| (f32 bits)   15: pad
//   packC[j] (48 B) = { x,y,z,etadot | A'[0..7] }  (f32)
//   Block 0 additionally emits fc16 (f16 MFMA B-frags) and gateC[18].
// ---------------------------------------------------------------------------
__global__ __launch_bounds__(256) void k1_precompute(
    const float* __restrict__ feats,   // [TOTAL][35]
    const float* __restrict__ pW,      // point_W  [10][8]
    const float* __restrict__ pBN,     // point_bn [4][8]
    const float* __restrict__ eW,      // eta_W    [32][8]
    const float* __restrict__ eBN,     // eta_bn   [4][8]
    const float* __restrict__ mW,      // mu_W     [32][8]
    const float* __restrict__ mBN,     // mu_bn    [4][8]
    const float* __restrict__ gW,      // gamma_W  [35][32]
    const float* __restrict__ gBN,     // gamma_bn [4][32]
    const float* __restrict__ mapW,    // map_W    [24]
    const float* __restrict__ mapBN,   // map_bn   [4]
    const float* __restrict__ fcW,     // [32][128]
    unsigned* __restrict__ packN,
    float* __restrict__ packC,
    unsigned* __restrict__ fc16,       // 512 frags x 16 B
    float* __restrict__ gateC)         // 18 f32
{
    __shared__ float sG[35 * 32];      // 4480 B
    __shared__ float sE[32 * 8];       // 1024 B
    __shared__ float sM[32 * 8];       // 1024 B

    const int tid = threadIdx.x;
    const int j = blockIdx.x * 256 + tid;

    // ---- issue feats loads first (overlap with staging + barrier) -------
    float f[36];
    {
        const float* row = feats + (size_t)j * 35;
#pragma unroll
        for (int q4 = 0; q4 < 8; ++q4) {
            const float4 v = *(const float4*)(row + q4 * 4);
            f[q4 * 4 + 0] = v.x; f[q4 * 4 + 1] = v.y;
            f[q4 * 4 + 2] = v.z; f[q4 * 4 + 3] = v.w;
        }
        const float4 v = *(const float4*)(row + 31);   // overlaps f[31]
        f[31] = v.x; f[32] = v.y; f[33] = v.z; f[34] = v.w;
    }

    // ---- stage weights (coalesced, once per block) ----------------------
    for (int i = tid; i < 1120; i += 256) sG[i] = gW[i];
    sE[tid] = eW[tid];
    sM[tid] = mW[tid];
    __syncthreads();

    const float x = f[0], y = f[1], z = f[2];
    const float pp = x * x + y * y + z * z;

    // ---- G = f @ gamma_W (weights broadcast from LDS) -------------------
    float G[32];
#pragma unroll
    for (int q = 0; q < 32; ++q) G[q] = 0.f;
#pragma unroll 5
    for (int d = 0; d < 35; ++d) {
        const float fd = f[d];
        const float4* w4 = (const float4*)(sG + d * 32);
#pragma unroll
        for (int q4 = 0; q4 < 8; ++q4) {
            const float4 w = w4[q4];
            G[q4 * 4 + 0] = fmaf(fd, w.x, G[q4 * 4 + 0]);
            G[q4 * 4 + 1] = fmaf(fd, w.y, G[q4 * 4 + 1]);
            G[q4 * 4 + 2] = fmaf(fd, w.z, G[q4 * 4 + 2]);
            G[q4 * 4 + 3] = fmaf(fd, w.w, G[q4 * 4 + 3]);
        }
    }
#pragma unroll
    for (int q = 0; q < 32; ++q) {
        const float g = gBN[q], b = gBN[32 + q], m = gBN[64 + q], v = gBN[96 + q];
        const float s = g / sqrtf(v + EPSB);
        G[q] = fmaf(G[q], s, b - m * s);
    }

    // ---- eta / mu (8ch) -> scalar dots with map_W -----------------------
    float eta[8], mu[8];
#pragma unroll
    for (int q = 0; q < 8; ++q) { eta[q] = 0.f; mu[q] = 0.f; }
#pragma unroll 4
    for (int i = 0; i < 32; ++i) {
        const float fi = f[3 + i];
        const float4* e4 = (const float4*)(sE + i * 8);
        const float4* m4 = (const float4*)(sM + i * 8);
#pragma unroll
        for (int h = 0; h < 2; ++h) {
            const float4 we = e4[h], wm = m4[h];
            eta[h * 4 + 0] = fmaf(fi, we.x, eta[h * 4 + 0]);
            eta[h * 4 + 1] = fmaf(fi, we.y, eta[h * 4 + 1]);
            eta[h * 4 + 2] = fmaf(fi, we.z, eta[h * 4 + 2]);
            eta[h * 4 + 3] = fmaf(fi, we.w, eta[h * 4 + 3]);
            mu[h * 4 + 0] = fmaf(fi, wm.x, mu[h * 4 + 0]);
            mu[h * 4 + 1] = fmaf(fi, wm.y, mu[h * 4 + 1]);
            mu[h * 4 + 2] = fmaf(fi, wm.z, mu[h * 4 + 2]);
            mu[h * 4 + 3] = fmaf(fi, wm.w, mu[h * 4 + 3]);
        }
    }
    float etadot = 0.f, Mdot = 0.f;
#pragma unroll
    for (int q = 0; q < 8; ++q) {
        const float ge = eBN[q], be = eBN[8 + q], me = eBN[16 + q], ve = eBN[24 + q];
        const float se = ge / sqrtf(ve + EPSB);
        etadot = fmaf(fmaf(eta[q], se, be - me * se), mapW[8 + q], etadot);
        const float gm = mBN[q], bm = mBN[8 + q], mm = mBN[16 + q], vm = mBN[24 + q];
        const float sm = gm / sqrtf(vm + EPSB);
        Mdot = fmaf(fmaf(mu[q], sm, bm - mm * sm), mapW[16 + q], Mdot);
    }

    // ---- point branch split: neighbor part Bn', center part A' ----------
    float Bnp[8], Ap[8];
#pragma unroll
    for (int q = 0; q < 8; ++q) {
        const float pw0 = pW[q];
        const float g = pBN[q], b = pBN[8 + q], m = pBN[16 + q], v = pBN[24 + q];
        const float s = g / sqrtf(v + EPSB);
        const float t = b - m * s;
        const float Braw = pp * pw0
            + x * (pW[32 + q] - pW[56 + q])
            + y * (pW[40 + q] - pW[64 + q])
            + z * (pW[48 + q] - pW[72 + q]);
        const float Araw = pp * pw0
            + x * (pW[8 + q]  + pW[56 + q])
            + y * (pW[16 + q] + pW[64 + q])
            + z * (pW[24 + q] + pW[72 + q]);
        Bnp[q] = Braw * s;
        Ap[q]  = fmaf(Araw, s, t);
    }

    // ---- quant G: bytes [c0,c2,c1,c3] (pairs channel-ordered in k2) -----
    float gmax = 0.f;
#pragma unroll
    for (int q = 0; q < 32; ++q) gmax = fmaxf(gmax, fabsf(G[q]));
    const float inv = (gmax > 0.f) ? (127.f / gmax) : 0.f;
    unsigned gq[8];
#pragma unroll
    for (int qd = 0; qd < 8; ++qd) {
        const unsigned u0 = (unsigned)((int)rintf(G[4*qd+0] * inv) + 128) & 0xffu;
        const unsigned u1 = (unsigned)((int)rintf(G[4*qd+1] * inv) + 128) & 0xffu;
        const unsigned u2 = (unsigned)((int)rintf(G[4*qd+2] * inv) + 128) & 0xffu;
        const unsigned u3 = (unsigned)((int)rintf(G[4*qd+3] * inv) + 128) & 0xffu;
        gq[qd] = u0 | (u2 << 8) | (u1 << 16) | (u3 << 24);
    }
    union { float f; unsigned u; } sc; sc.f = gmax;

    uint4* PN = (uint4*)(packN + (size_t)j * NPACK_DW);
    PN[0] = make_uint4(h2u(x, y), h2u(z, Mdot), h2u(Bnp[0], Bnp[1]), h2u(Bnp[2], Bnp[3]));
    PN[1] = make_uint4(h2u(Bnp[4], Bnp[5]), h2u(Bnp[6], Bnp[7]), gq[0], gq[1]);
    PN[2] = make_uint4(gq[2], gq[3], gq[4], gq[5]);
    PN[3] = make_uint4(gq[6], gq[7], sc.u, 0u);

    float4* PC = (float4*)(packC + (size_t)j * CPACK);
    PC[0] = make_float4(x, y, z, etadot);
    PC[1] = make_float4(Ap[0], Ap[1], Ap[2], Ap[3]);
    PC[2] = make_float4(Ap[4], Ap[5], Ap[6], Ap[7]);

    // ---- block 0: fc_W -> f16 fragments + folded gate constants ---------
    if (blockIdx.x == 0) {
        for (int fi = tid; fi < 512; fi += 256) {
            const int lm = fi & 15, nt = (fi >> 4) & 7, lq = fi >> 7;
            unsigned dws[4];
#pragma unroll
            for (int p = 0; p < 4; ++p) {
                const float a = fcW[(8 * lq + 2 * p)     * 128 + nt * 16 + lm];
                const float b = fcW[(8 * lq + 2 * p + 1) * 128 + nt * 16 + lm];
                dws[p] = h2u(a, b);
            }
            ((uint4*)fc16)[fi] = make_uint4(dws[0], dws[1], dws[2], dws[3]);
        }
        if (tid == 0) {
#pragma unroll
            for (int q = 0; q < 8; ++q) {
                const float g = pBN[q], v = pBN[24 + q];
                const float s = g / sqrtf(v + EPSB);
                gateC[q]     = 2.f * pW[q] * s;   // W0p
                gateC[8 + q] = mapW[q];           // mW0
            }
            const float g = mapBN[0], b = mapBN[1], m = mapBN[2], v = mapBN[3];
            const float ms = g / sqrtf(v + EPSB);
            gateC[16] = ms;
            gateC[17] = b - m * ms;
        }
    }
}

// ---------------------------------------------------------------------------
// Kernel 2 (fused): gather + gate + packed-f16 max-pool + f16 MFMA fc.
// 32 centers/block, 8 lanes/center, 2 gathers/lane. Dequant via the f16
// bit-trick: (dw & 0x00FF00FF)|0x64006400 == packed f16 (1024+u8).
// ---------------------------------------------------------------------------
__global__ __launch_bounds__(256) void k2_aggregate_fc(
    const int* __restrict__ idx,      // [TOTAL][16]
    const unsigned* __restrict__ packN,
    const float* __restrict__ packC,
    const unsigned* __restrict__ fc16,
    const float* __restrict__ gateC,
    float* __restrict__ out)          // [TOTAL][128]
{
    __shared__ __align__(16) unsigned short sPool[32 * 40];  // f16 pooled tile

    // ---- XCD-batch affinity remap (grid = 4096, 8 XCDs round-robin) ----
    const int bid  = blockIdx.x;
    const int xcd  = bid & 7, slot = bid >> 3;
    const int cb   = (xcd < 4) ? (slot * 4 + xcd)
                               : (2048 + slot * 4 + (xcd - 4));
    const int cbase = cb * 32;

    const int tid  = threadIdx.x;
    const int cl   = tid >> 3;        // local center 0..31
    const int ks   = tid & 7;
    const int c    = cbase + cl;
    const int lane = tid & 63;
    const int w    = tid >> 6;        // wave 0..3
    const int lm   = lane & 15, lq = lane >> 4;

    // ---- B fragments: preshuffled f16, 2x b128 --------------------------
    f16x8 bfrag[2];
#pragma unroll
    for (int ntj = 0; ntj < 2; ++ntj) {
        union { uint4 u4; f16x8 v; } cv;
        cv.u4 = ((const uint4*)fc16)[(lq * 8 + 2 * w + ntj) * 16 + lm];
        bfrag[ntj] = cv.v;
    }

    // ---- gate constants (uniform scalar loads) --------------------------
    const float ms = gateC[16], mt = gateC[17];
    float W0p[8], mW0[8];
#pragma unroll
    for (int q = 0; q < 8; ++q) { W0p[q] = gateC[q]; mW0[q] = gateC[8 + q]; }

    const float4* PC = (const float4*)(packC + (size_t)c * CPACK);
    const float4 c0 = PC[0], c1 = PC[1], c2 = PC[2];
    const float px = c0.x, py = c0.y, pz = c0.z, etadot = c0.w;
    const float Ap[8] = { c1.x, c1.y, c1.z, c1.w, c2.x, c2.y, c2.z, c2.w };

    const int2 ib2 = ((const int2*)idx)[c * 8 + ks];
    const int bbase = c & ~(N_PTS - 1);

    unsigned o16[16];
#pragma unroll
    for (int q = 0; q < 16; ++q) o16[q] = 0xFC00FC00u;   // (-inf, -inf)

    const uint4* P0 = (const uint4*)(packN + (size_t)(bbase + ib2.x) * NPACK_DW);
    const uint4* P1 = (const uint4*)(packN + (size_t)(bbase + ib2.y) * NPACK_DW);
    uint4 n0[4] = { P0[0], P0[1], P0[2], P0[3] };
    uint4 n1[4] = { P1[0], P1[1], P1[2], P1[3] };

#pragma unroll
    for (int k = 0; k < 2; ++k) {
        const uint4* N = k ? n1 : n0;
        const float2 xy = u2f2(N[0].x), zM = u2f2(N[0].y);
        const float dot3 = px * xy.x + py * xy.y + pz * zM.x;

        const unsigned bn[4] = { N[0].z, N[0].w, N[1].x, N[1].y };
        float pd = 0.f;
#pragma unroll
        for (int q = 0; q < 4; ++q) {
            const float2 bn2 = u2f2(bn[q]);
            const float u0 = Ap[2 * q]     + bn2.x - dot3 * W0p[2 * q];
            const float u1 = Ap[2 * q + 1] + bn2.y - dot3 * W0p[2 * q + 1];
            pd = fmaf(fmaxf(u0, 0.f), mW0[2 * q], pd);
            pd = fmaf(fmaxf(u1, 0.f), mW0[2 * q + 1], pd);
        }
        float s = fmaf(pd + etadot + zM.y, ms, mt);
        s = fmaxf(s, 0.f);

        // dequant+gate: value = t*(1024+u8) - 1152*t  (u8 = q+128)
        union { unsigned u; float f; } sc; sc.u = N[3].z;
        const float t = s * sc.f * (1.f / 127.f);
        const unsigned t2 = pkrtz(t, t);
        const float d = -1152.f * t;
        const unsigned d2 = pkrtz(d, d);

        const unsigned gd[8] = { N[1].z, N[1].w, N[2].x, N[2].y,
                                 N[2].z, N[2].w, N[3].x, N[3].y };
#pragma unroll
        for (int qd = 0; qd < 8; ++qd) {
            const unsigned dwv = gd[qd];
            const unsigned lo = (dwv & 0x00FF00FFu) | 0x64006400u;
            const unsigned hi = ((dwv >> 8) & 0x00FF00FFu) | 0x64006400u;
            o16[2 * qd]     = pk_max(o16[2 * qd],     pk_fma(lo, t2, d2));
            o16[2 * qd + 1] = pk_max(o16[2 * qd + 1], pk_fma(hi, t2, d2));
        }
    }

    // ---- 3-level packed max reduce across the 8-lane group --------------
#pragma unroll
    for (int q = 0; q < 16; ++q) {
        unsigned v = o16[q];
        v = pk_max(v, (unsigned)__shfl_xor((int)v, 1));
        v = pk_max(v, (unsigned)__shfl_xor((int)v, 2));
        v = pk_max(v, (unsigned)__shfl_xor((int)v, 4));
        o16[q] = v;
    }

    // lane ks owns channels 4ks..4ks+3 (f16), one 8 B store ---------------
    {
        uint2 pk;
        pk.x = o16[2 * ks];
        pk.y = o16[2 * ks + 1];
        *(uint2*)(sPool + cl * 40 + ks * 4) = pk;
    }
    __syncthreads();

    // ---- fc via MFMA: D[32 x 32cols per wave] = pooled(32x32) @ fcW -----
    f32x4 acc[2][2];
#pragma unroll
    for (int a = 0; a < 2; ++a)
#pragma unroll
        for (int b = 0; b < 2; ++b)
            acc[a][b] = (f32x4){0.f, 0.f, 0.f, 0.f};

#pragma unroll
    for (int mtile = 0; mtile < 2; ++mtile) {
        const f16x8 afrag = *(const f16x8*)(sPool + (mtile * 16 + lm) * 40 + lq * 8);
#pragma unroll
        for (int ntj = 0; ntj < 2; ++ntj)
            acc[mtile][ntj] = __builtin_amdgcn_mfma_f32_16x16x32_f16(
                afrag, bfrag[ntj], acc[mtile][ntj], 0, 0, 0);
    }

#pragma unroll
    for (int mtile = 0; mtile < 2; ++mtile)
#pragma unroll
        for (int ntj = 0; ntj < 2; ++ntj) {
            const int nt = 2 * w + ntj;
#pragma unroll
            for (int r = 0; r < 4; ++r)
                __builtin_nontemporal_store(acc[mtile][ntj][r],
                    &out[(size_t)(cbase + mtile * 16 + lq * 4 + r) * 128 + nt * 16 + lm]);
        }
}

// ---------------------------------------------------------------------------
extern "C" void kernel_launch(void* const* d_in, const int* in_sizes, int n_in,
                              void* d_out, int out_size, void* d_ws, size_t ws_size,
                              hipStream_t stream) {
    const float* feats    = (const float*)d_in[0];
    const int*   idx      = (const int*)  d_in[1];
    const float* point_W  = (const float*)d_in[2];
    const float* point_bn = (const float*)d_in[3];
    const float* eta_W    = (const float*)d_in[4];
    const float* eta_bn   = (const float*)d_in[5];
    const float* mu_W     = (const float*)d_in[6];
    const float* mu_bn    = (const float*)d_in[7];
    const float* gamma_W  = (const float*)d_in[8];
    const float* gamma_bn = (const float*)d_in[9];
    const float* map_W    = (const float*)d_in[10];
    const float* map_bn   = (const float*)d_in[11];
    const float* fc_W     = (const float*)d_in[12];
    float* out = (float*)d_out;

    unsigned* packN = (unsigned*)d_ws;                            // 8 MB
    float*    packC = (float*)(packN + (size_t)TOTAL * NPACK_DW); // 6 MB
    unsigned* fc16  = (unsigned*)(packC + (size_t)TOTAL * CPACK); // 8 KB
    float*    gateC = (float*)(fc16 + 2048);                      // 72 B

    hipLaunchKernelGGL(k1_precompute, dim3(TOTAL / 256), dim3(256), 0, stream,
                       feats, point_W, point_bn, eta_W, eta_bn, mu_W, mu_bn,
                       gamma_W, gamma_bn, map_W, map_bn, fc_W,
                       packN, packC, fc16, gateC);
    hipLaunchKernelGGL(k2_aggregate_fc, dim3(TOTAL / 32), dim3(256), 0, stream,
                       idx, packN, packC, fc16, gateC, out);
}

// Round 11
// 146.205 us; speedup vs baseline: 1.1503x; 1.1503x over previous
//
#include <hip/hip_runtime.h>
#include <hip/hip_fp16.h>
#include <math.h>

#define N_PTS   65536
#define BATCH   2
#define TOTAL   (BATCH * N_PTS)   // 131072
#define NPACK_DW 16               // dwords per point, neighbor payload (64 B)
#define CPACK   12                // floats per point, center payload
#define EPSB    1e-5f

typedef float  f32x4  __attribute__((ext_vector_type(4)));
typedef _Float16 f16x8 __attribute__((ext_vector_type(8)));

static __device__ inline unsigned h2u(float a, float b) {
    __half2 h = __floats2half2_rn(a, b);
    union { __half2 h; unsigned u; } cv; cv.h = h; return cv.u;
}
static __device__ inline float2 u2f2(unsigned u) {
    union { unsigned u; __half2 h; } cv; cv.u = u; return __half22float2(cv.h);
}
static __device__ inline unsigned pk_max(unsigned a, unsigned b) {
    unsigned r; asm("v_pk_max_f16 %0, %1, %2" : "=v"(r) : "v"(a), "v"(b)); return r;
}
static __device__ inline unsigned pk_fma(unsigned a, unsigned b, unsigned c) {
    unsigned r; asm("v_pk_fma_f16 %0, %1, %2, %3" : "=v"(r) : "v"(a), "v"(b), "v"(c)); return r;
}
static __device__ inline unsigned pkrtz(float a, float b) {
    unsigned r; asm("v_cvt_pkrtz_f16_f32 %0, %1, %2" : "=v"(r) : "v"(a), "v"(b)); return r;
}

// ---------------------------------------------------------------------------
// Kernel 1 (MFMA): per-wave 16-point tile.
//   [G(32) | eta(8) | mu(8)] = f16(feats[:,3:35]) @ f16(W)  via 3x
//   mfma_f32_16x16x32_f16 (A: row=lane&15,k=8*(lane>>4)+j; B: col=lane&15,
//   same k; D: row=4*(lane>>4)+r, col=lane&15  — mapping verified by k2).
//   xyz rank-3 term + BN folds + gate dots + Bnp/Ap + int8 quant in epilogue;
//   packN/packC rows assembled in per-wave LDS, stored coalesced.
// ---------------------------------------------------------------------------
__global__ __launch_bounds__(256) void k1_precompute(
    const float* __restrict__ feats,   // [TOTAL][35]
    const float* __restrict__ pW,      // point_W  [10][8]
    const float* __restrict__ pBN,     // point_bn [4][8]
    const float* __restrict__ eW,      // eta_W    [32][8]
    const float* __restrict__ eBN,     // eta_bn   [4][8]
    const float* __restrict__ mW,      // mu_W     [32][8]
    const float* __restrict__ mBN,     // mu_bn    [4][8]
    const float* __restrict__ gW,      // gamma_W  [35][32]
    const float* __restrict__ gBN,     // gamma_bn [4][32]
    const float* __restrict__ mapW,    // map_W    [24]
    const float* __restrict__ mapBN,   // map_bn   [4]
    const float* __restrict__ fcW,     // [32][128]
    unsigned* __restrict__ packN,
    float* __restrict__ packC,
    unsigned* __restrict__ fc16,       // 512 frags x 16 B
    float* __restrict__ gateC)         // 18 f32
{
    __shared__ __align__(16) unsigned char sPk[4][1792];  // per-wave 16x64 + 16x48

    const int tid  = threadIdx.x;
    const int lane = tid & 63, wv = tid >> 6;
    const int lm   = lane & 15, lq = lane >> 4;
    const int pt0  = blockIdx.x * 64 + wv * 16;

    // ---------------- loop-invariant per-lane constants -----------------
    f16x8 bG0, bG1, bEM;
    {
        union { unsigned short u[8]; f16x8 v; } c0, c1, c2;
#pragma unroll
        for (int j = 0; j < 8; ++j) {
            const int k = 8 * lq + j;
            c0.u[j] = __half_as_ushort(__float2half_rn(gW[(3 + k) * 32 + lm]));
            c1.u[j] = __half_as_ushort(__float2half_rn(gW[(3 + k) * 32 + 16 + lm]));
            const float w2 = (lm < 8) ? eW[k * 8 + lm] : mW[k * 8 + (lm - 8)];
            c2.u[j] = __half_as_ushort(__float2half_rn(w2));
        }
        bG0 = c0.v; bG1 = c1.v; bEM = c2.v;
    }
    // gamma BN fold (cols lm and 16+lm) + xyz row-weights (gamma rows 0..2)
    const float sA = gBN[lm]      / sqrtf(gBN[96 + lm]  + EPSB);
    const float tA = gBN[32 + lm] - gBN[64 + lm] * sA;
    const float sB = gBN[16 + lm] / sqrtf(gBN[112 + lm] + EPSB);
    const float tB = gBN[48 + lm] - gBN[80 + lm] * sB;
    const float w0a = gW[lm],      w1a = gW[32 + lm],      w2a = gW[64 + lm];
    const float w0b = gW[16 + lm], w1b = gW[48 + lm],      w2b = gW[80 + lm];
    // eta/mu fold + map weight (col lm of [eta|mu])
    float sE_, tE_, mpw;
    if (lm < 8) {
        sE_ = eBN[lm] / sqrtf(eBN[24 + lm] + EPSB);
        tE_ = eBN[8 + lm] - eBN[16 + lm] * sE_;
        mpw = mapW[8 + lm];
    } else {
        const int qq = lm - 8;
        sE_ = mBN[qq] / sqrtf(mBN[24 + qq] + EPSB);
        tE_ = mBN[8 + qq] - mBN[16 + qq] * sE_;
        mpw = mapW[16 + qq];
    }
    // point-branch constants (lane lm<8: Bnp[q=lm]; lm>=8: Ap[q=lm-8])
    const int  q   = lm & 7;
    const bool isB = lm < 8;
    const float pw0 = pW[q];
    const float sp  = pBN[q] / sqrtf(pBN[24 + q] + EPSB);
    const float tp  = pBN[8 + q] - pBN[16 + q] * sp;
    float cxx, cyy, czz;
    if (isB) { cxx = pW[32+q]-pW[56+q]; cyy = pW[40+q]-pW[64+q]; czz = pW[48+q]-pW[72+q]; }
    else     { cxx = pW[8+q] +pW[56+q]; cyy = pW[16+q]+pW[64+q]; czz = pW[24+q]+pW[72+q]; }

    // ---------------- A fragment + xyz of owned rows ---------------------
    f16x8 afrag;
    {
        const float* ar = feats + (size_t)(pt0 + lm) * 35 + 3 + 8 * lq;
        const float4 a0 = *(const float4*)ar;
        const float4 a1 = *(const float4*)(ar + 4);
        union { unsigned u[4]; f16x8 v; } cv;
        cv.u[0] = h2u(a0.x, a0.y); cv.u[1] = h2u(a0.z, a0.w);
        cv.u[2] = h2u(a1.x, a1.y); cv.u[3] = h2u(a1.z, a1.w);
        afrag = cv.v;
    }
    float X[4], Y[4], Z[4], PP[4];
#pragma unroll
    for (int r = 0; r < 4; ++r) {
        const float* rr = feats + (size_t)(pt0 + 4 * lq + r) * 35;
        X[r] = rr[0]; Y[r] = rr[1]; Z[r] = rr[2];
        PP[r] = X[r]*X[r] + Y[r]*Y[r] + Z[r]*Z[r];
    }

    // ---------------- MFMAs ---------------------------------------------
    f32x4 aG0 = {0.f,0.f,0.f,0.f}, aG1 = {0.f,0.f,0.f,0.f}, aEM = {0.f,0.f,0.f,0.f};
    aG0 = __builtin_amdgcn_mfma_f32_16x16x32_f16(afrag, bG0, aG0, 0, 0, 0);
    aG1 = __builtin_amdgcn_mfma_f32_16x16x32_f16(afrag, bG1, aG1, 0, 0, 0);
    aEM = __builtin_amdgcn_mfma_f32_16x16x32_f16(afrag, bEM, aEM, 0, 0, 0);

    // ---------------- epilogue -------------------------------------------
    float G0[4], G1[4], eD[4], mD[4], BA[4], gm[4], iv[4];
#pragma unroll
    for (int r = 0; r < 4; ++r) {
        G0[r] = fmaf(aG0[r] + X[r]*w0a + Y[r]*w1a + Z[r]*w2a, sA, tA);
        G1[r] = fmaf(aG1[r] + X[r]*w0b + Y[r]*w1b + Z[r]*w2b, sB, tB);
        float v = fmaf(aEM[r], sE_, tE_) * mpw;
        v += __shfl_xor(v, 1);
        v += __shfl_xor(v, 2);
        v += __shfl_xor(v, 4);
        const float o = __shfl_xor(v, 8);
        eD[r] = isB ? v : o;     // etadot (eta cols live in lanes lm<8)
        mD[r] = isB ? o : v;     // Mdot
        const float raw = PP[r]*pw0 + X[r]*cxx + Y[r]*cyy + Z[r]*czz;
        BA[r] = isB ? raw * sp : fmaf(raw, sp, tp);
        float m = fmaxf(fabsf(G0[r]), fabsf(G1[r]));
        m = fmaxf(m, __shfl_xor(m, 1));
        m = fmaxf(m, __shfl_xor(m, 2));
        m = fmaxf(m, __shfl_xor(m, 4));
        m = fmaxf(m, __shfl_xor(m, 8));
        gm[r] = m;
        iv[r] = (m > 0.f) ? (127.f / m) : 0.f;
    }

    // ---------------- LDS assembly (per-wave region) ---------------------
    unsigned char* PNl = sPk[wv];           // [16][64]
    unsigned char* PCl = sPk[wv] + 1024;    // [16][48]
    const int pos = (0x3120 >> ((lm & 3) * 4)) & 0xF;   // byte perm 0,2,1,3
    const int gb0 = 24 + ((lm >> 2) << 2) + pos;
#pragma unroll
    for (int r = 0; r < 4; ++r) {
        const int row = 4 * lq + r;
        unsigned char* RN = PNl + row * 64;
        RN[gb0]      = (unsigned char)((int)rintf(G0[r] * iv[r]) + 128);  // ch lm
        RN[gb0 + 16] = (unsigned char)((int)rintf(G1[r] * iv[r]) + 128);  // ch lm+16
        if (isB) {
            *(unsigned short*)(RN + 8 + 2 * q) =
                __half_as_ushort(__float2half_rn(BA[r]));
        } else {
            *(float*)(PCl + row * 48 + 16 + 4 * q) = BA[r];
        }
        if (lm == 0)
            *(float4*)(PCl + row * 48) = make_float4(X[r], Y[r], Z[r], eD[r]);
        if (lm == 1) {
            *(unsigned*)(RN + 0) = h2u(X[r], Y[r]);
            *(unsigned*)(RN + 4) = h2u(Z[r], mD[r]);
        }
        if (lm == 2) {
            union { float f; unsigned u; } sc; sc.f = gm[r];
            *(unsigned*)(RN + 56) = sc.u;
            *(unsigned*)(RN + 60) = 0u;
        }
    }

    // ---------------- coalesced readback + global store ------------------
    {
        const uint4 v = *(const uint4*)(PNl + (lane >> 2) * 64 + (lane & 3) * 16);
        ((uint4*)packN)[(size_t)(pt0 + (lane >> 2)) * 4 + (lane & 3)] = v;
    }
    if (lane < 48) {
        const int pr = lane / 3, pc = lane % 3;
        const uint4 v = *(const uint4*)(PCl + pr * 48 + pc * 16);
        ((uint4*)packC)[(size_t)(pt0 + pr) * 3 + pc] = v;
    }

    // ---- block 0: fc_W -> f16 fragments + folded gate constants ---------
    if (blockIdx.x == 0) {
        for (int fi = tid; fi < 512; fi += 256) {
            const int flm = fi & 15, nt = (fi >> 4) & 7, flq = fi >> 7;
            unsigned dws[4];
#pragma unroll
            for (int p = 0; p < 4; ++p) {
                const float a = fcW[(8 * flq + 2 * p)     * 128 + nt * 16 + flm];
                const float b = fcW[(8 * flq + 2 * p + 1) * 128 + nt * 16 + flm];
                dws[p] = h2u(a, b);
            }
            ((uint4*)fc16)[fi] = make_uint4(dws[0], dws[1], dws[2], dws[3]);
        }
        if (tid == 0) {
#pragma unroll
            for (int qq = 0; qq < 8; ++qq) {
                const float g = pBN[qq], v = pBN[24 + qq];
                const float s = g / sqrtf(v + EPSB);
                gateC[qq]     = 2.f * pW[qq] * s;   // W0p
                gateC[8 + qq] = mapW[qq];           // mW0
            }
            const float g = mapBN[0], b = mapBN[1], m = mapBN[2], v = mapBN[3];
            const float ms = g / sqrtf(v + EPSB);
            gateC[16] = ms;
            gateC[17] = b - m * ms;
        }
    }
}

// ---------------------------------------------------------------------------
// Kernel 2 (fused): gather + gate + packed-f16 max-pool + f16 MFMA fc.
// 32 centers/block, 8 lanes/center, 2 gathers/lane. Dequant via the f16
// bit-trick: (dw & 0x00FF00FF)|0x64006400 == packed f16 (1024+u8).
// ---------------------------------------------------------------------------
__global__ __launch_bounds__(256) void k2_aggregate_fc(
    const int* __restrict__ idx,      // [TOTAL][16]
    const unsigned* __restrict__ packN,
    const float* __restrict__ packC,
    const unsigned* __restrict__ fc16,
    const float* __restrict__ gateC,
    float* __restrict__ out)          // [TOTAL][128]
{
    __shared__ __align__(16) unsigned short sPool[32 * 40];  // f16 pooled tile

    // ---- XCD-batch affinity remap (grid = 4096, 8 XCDs round-robin) ----
    const int bid  = blockIdx.x;
    const int xcd  = bid & 7, slot = bid >> 3;
    const int cb   = (xcd < 4) ? (slot * 4 + xcd)
                               : (2048 + slot * 4 + (xcd - 4));
    const int cbase = cb * 32;

    const int tid  = threadIdx.x;
    const int cl   = tid >> 3;        // local center 0..31
    const int ks   = tid & 7;
    const int c    = cbase + cl;
    const int lane = tid & 63;
    const int w    = tid >> 6;        // wave 0..3
    const int lm   = lane & 15, lq = lane >> 4;

    // ---- B fragments: preshuffled f16, 2x b128 --------------------------
    f16x8 bfrag[2];
#pragma unroll
    for (int ntj = 0; ntj < 2; ++ntj) {
        union { uint4 u4; f16x8 v; } cv;
        cv.u4 = ((const uint4*)fc16)[(lq * 8 + 2 * w + ntj) * 16 + lm];
        bfrag[ntj] = cv.v;
    }

    // ---- gate constants (uniform scalar loads) --------------------------
    const float ms = gateC[16], mt = gateC[17];
    float W0p[8], mW0[8];
#pragma unroll
    for (int qq = 0; qq < 8; ++qq) { W0p[qq] = gateC[qq]; mW0[qq] = gateC[8 + qq]; }

    const float4* PC = (const float4*)(packC + (size_t)c * CPACK);
    const float4 c0 = PC[0], c1 = PC[1], c2 = PC[2];
    const float px = c0.x, py = c0.y, pz = c0.z, etadot = c0.w;
    const float Ap[8] = { c1.x, c1.y, c1.z, c1.w, c2.x, c2.y, c2.z, c2.w };

    const int2 ib2 = ((const int2*)idx)[c * 8 + ks];
    const int bbase = c & ~(N_PTS - 1);

    unsigned o16[16];
#pragma unroll
    for (int qq = 0; qq < 16; ++qq) o16[qq] = 0xFC00FC00u;   // (-inf, -inf)

    const uint4* P0 = (const uint4*)(packN + (size_t)(bbase + ib2.x) * NPACK_DW);
    const uint4* P1 = (const uint4*)(packN + (size_t)(bbase + ib2.y) * NPACK_DW);
    uint4 n0[4] = { P0[0], P0[1], P0[2], P0[3] };
    uint4 n1[4] = { P1[0], P1[1], P1[2], P1[3] };

#pragma unroll
    for (int k = 0; k < 2; ++k) {
        const uint4* N = k ? n1 : n0;
        const float2 xy = u2f2(N[0].x), zM = u2f2(N[0].y);
        const float dot3 = px * xy.x + py * xy.y + pz * zM.x;

        const unsigned bn[4] = { N[0].z, N[0].w, N[1].x, N[1].y };
        float pd = 0.f;
#pragma unroll
        for (int qq = 0; qq < 4; ++qq) {
            const float2 bn2 = u2f2(bn[qq]);
            const float u0 = Ap[2 * qq]     + bn2.x - dot3 * W0p[2 * qq];
            const float u1 = Ap[2 * qq + 1] + bn2.y - dot3 * W0p[2 * qq + 1];
            pd = fmaf(fmaxf(u0, 0.f), mW0[2 * qq], pd);
            pd = fmaf(fmaxf(u1, 0.f), mW0[2 * qq + 1], pd);
        }
        float s = fmaf(pd + etadot + zM.y, ms, mt);
        s = fmaxf(s, 0.f);

        // dequant+gate: value = t*(1024+u8) - 1152*t  (u8 = q+128)
        union { unsigned u; float f; } sc; sc.u = N[3].z;
        const float t = s * sc.f * (1.f / 127.f);
        const unsigned t2 = pkrtz(t, t);
        const float d = -1152.f * t;
        const unsigned d2 = pkrtz(d, d);

        const unsigned gd[8] = { N[1].z, N[1].w, N[2].x, N[2].y,
                                 N[2].z, N[2].w, N[3].x, N[3].y };
#pragma unroll
        for (int qd = 0; qd < 8; ++qd) {
            const unsigned dwv = gd[qd];
            const unsigned lo = (dwv & 0x00FF00FFu) | 0x64006400u;
            const unsigned hi = ((dwv >> 8) & 0x00FF00FFu) | 0x64006400u;
            o16[2 * qd]     = pk_max(o16[2 * qd],     pk_fma(lo, t2, d2));
            o16[2 * qd + 1] = pk_max(o16[2 * qd + 1], pk_fma(hi, t2, d2));
        }
    }

    // ---- 3-level packed max reduce across the 8-lane group --------------
#pragma unroll
    for (int qq = 0; qq < 16; ++qq) {
        unsigned v = o16[qq];
        v = pk_max(v, (unsigned)__shfl_xor((int)v, 1));
        v = pk_max(v, (unsigned)__shfl_xor((int)v, 2));
        v = pk_max(v, (unsigned)__shfl_xor((int)v, 4));
        o16[qq] = v;
    }

    // lane ks owns channels 4ks..4ks+3 (f16), one 8 B store ---------------
    {
        uint2 pk;
        pk.x = o16[2 * ks];
        pk.y = o16[2 * ks + 1];
        *(uint2*)(sPool + cl * 40 + ks * 4) = pk;
    }
    __syncthreads();

    // ---- fc via MFMA: D[32 x 32cols per wave] = pooled(32x32) @ fcW -----
    f32x4 acc[2][2];
#pragma unroll
    for (int a = 0; a < 2; ++a)
#pragma unroll
        for (int b = 0; b < 2; ++b)
            acc[a][b] = (f32x4){0.f, 0.f, 0.f, 0.f};

#pragma unroll
    for (int mtile = 0; mtile < 2; ++mtile) {
        const f16x8 afrag = *(const f16x8*)(sPool + (mtile * 16 + lm) * 40 + lq * 8);
#pragma unroll
        for (int ntj = 0; ntj < 2; ++ntj)
            acc[mtile][ntj] = __builtin_amdgcn_mfma_f32_16x16x32_f16(
                afrag, bfrag[ntj], acc[mtile][ntj], 0, 0, 0);
    }

#pragma unroll
    for (int mtile = 0; mtile < 2; ++mtile)
#pragma unroll
        for (int ntj = 0; ntj < 2; ++ntj) {
            const int nt = 2 * w + ntj;
#pragma unroll
            for (int r = 0; r < 4; ++r)
                __builtin_nontemporal_store(acc[mtile][ntj][r],
                    &out[(size_t)(cbase + mtile * 16 + lq * 4 + r) * 128 + nt * 16 + lm]);
        }
}

// ---------------------------------------------------------------------------
extern "C" void kernel_launch(void* const* d_in, const int* in_sizes, int n_in,
                              void* d_out, int out_size, void* d_ws, size_t ws_size,
                              hipStream_t stream) {
    const float* feats    = (const float*)d_in[0];
    const int*   idx      = (const int*)  d_in[1];
    const float* point_W  = (const float*)d_in[2];
    const float* point_bn = (const float*)d_in[3];
    const float* eta_W    = (const float*)d_in[4];
    const float* eta_bn   = (const float*)d_in[5];
    const float* mu_W     = (const float*)d_in[6];
    const float* mu_bn    = (const float*)d_in[7];
    const float* gamma_W  = (const float*)d_in[8];
    const float* gamma_bn = (const float*)d_in[9];
    const float* map_W    = (const float*)d_in[10];
    const float* map_bn   = (const float*)d_in[11];
    const float* fc_W     = (const float*)d_in[12];
    float* out = (float*)d_out;

    unsigned* packN = (unsigned*)d_ws;                            // 8 MB
    float*    packC = (float*)(packN + (size_t)TOTAL * NPACK_DW); // 6 MB
    unsigned* fc16  = (unsigned*)(packC + (size_t)TOTAL * CPACK); // 8 KB
    float*    gateC = (float*)(fc16 + 2048);                      // 72 B

    hipLaunchKernelGGL(k1_precompute, dim3(TOTAL / 64), dim3(256), 0, stream,
                       feats, point_W, point_bn, eta_W, eta_bn, mu_W, mu_bn,
                       gamma_W, gamma_bn, map_W, map_bn, fc_W,
                       packN, packC, fc16, gateC);
    hipLaunchKernelGGL(k2_aggregate_fc, dim3(TOTAL / 32), dim3(256), 0, stream,
                       idx, packN, packC, fc16, gateC, out);
}